// Round 1
// baseline (889.555 us; speedup 1.0000x reference)
//
#include <hip/hip_runtime.h>

#define D        128
#define N_GRAPHS 64
#define N_CLS    16
#define RED_NB   32

// ---------------- CSR build ----------------

__global__ void k_deg(const int* __restrict__ dst, int* __restrict__ deg, int E) {
    int e = blockIdx.x * 256 + threadIdx.x;
    if (e < E) atomicAdd(&deg[dst[e]], 1);
}

__global__ void k_scan1(const int* __restrict__ deg, int* __restrict__ rowptr,
                        int* __restrict__ bsum, int N) {
    __shared__ int sh[1024];
    int t = threadIdx.x;
    int i = blockIdx.x * 1024 + t;
    int v = (i < N) ? deg[i] : 0;
    sh[t] = v;
    __syncthreads();
    for (int off = 1; off < 1024; off <<= 1) {
        int tmp = (t >= off) ? sh[t - off] : 0;
        __syncthreads();
        sh[t] += tmp;
        __syncthreads();
    }
    if (i < N) rowptr[i + 1] = sh[t];
    if (t == 1023) bsum[blockIdx.x] = sh[1023];
}

__global__ void k_scan2(const int* __restrict__ bsum, int* __restrict__ boff, int nch) {
    if (threadIdx.x == 0 && blockIdx.x == 0) {
        int run = 0;
        for (int j = 0; j < nch; j++) { boff[j] = run; run += bsum[j]; }
    }
}

__global__ void k_scan3(const int* __restrict__ deg, int* __restrict__ rowptr,
                        const int* __restrict__ boff, float* __restrict__ invdeg, int N) {
    int i = blockIdx.x * 256 + threadIdx.x;
    if (i < N) {
        rowptr[i + 1] += boff[i >> 10];
        int d = deg[i];
        invdeg[i] = 1.0f / (float)(d > 1 ? d : 1);
        if (i == 0) rowptr[0] = 0;
    }
}

__global__ void k_scatter(const int* __restrict__ src, const int* __restrict__ dst,
                          const int* __restrict__ rowptr, int* __restrict__ cursor,
                          int* __restrict__ csr, int E) {
    int e = blockIdx.x * 256 + threadIdx.x;
    if (e < E) {
        int d = dst[e];
        int p = atomicAdd(&cursor[d], 1);
        csr[rowptr[d] + p] = src[e];
    }
}

__global__ void k_hist(const int* __restrict__ gid, int* __restrict__ gcnt, int N) {
    __shared__ int lh[N_GRAPHS];
    int t = threadIdx.x;
    if (t < N_GRAPHS) lh[t] = 0;
    __syncthreads();
    int i = blockIdx.x * 256 + t;
    if (i < N) atomicAdd(&lh[gid[i]], 1);
    __syncthreads();
    if (t < N_GRAPHS && lh[t] > 0) atomicAdd(&gcnt[t], lh[t]);
}

// ---------------- neighbor mean aggregation (gather over CSR) ----------------
// one block (128 threads) per destination node; lanes = feature columns.

__global__ void k_agg(const float* __restrict__ feat, const int* __restrict__ rowptr,
                      const int* __restrict__ csr, const float* __restrict__ invdeg,
                      float* __restrict__ out) {
    int n = blockIdx.x;
    int c = threadIdx.x;
    int r0 = rowptr[n], r1 = rowptr[n + 1];
    float acc = 0.f;
    for (int e = r0; e < r1; e++) {
        int s = csr[e];
        acc += feat[s * D + c];
    }
    out[n * D + c] = acc * invdeg[n];
}

// ---------------- layer-1 fused dual-matmul + bias + relu ----------------
// x1[n][:] = relu(h[n]@W1s + neigh[n]@W1n + b1). One node per thread,
// acc[128] in VGPRs; A staged in LDS (pad-17: conflict-free per-lane reads);
// W row addresses are wave-uniform -> scalar/broadcast loads.

__global__ __launch_bounds__(256) void k_mm1(
    const float* __restrict__ h, const float* __restrict__ nb,
    const float* __restrict__ Ws, const float* __restrict__ Wn,
    const float* __restrict__ b, float* __restrict__ x1, int N) {
    __shared__ float ht[256][17];
    __shared__ float gt[256][17];
    int t = threadIdx.x;
    int n = blockIdx.x * 256 + t;
    bool valid = n < N;
    float acc[D];
#pragma unroll
    for (int c = 0; c < D; c++) acc[c] = 0.f;

    for (int k0 = 0; k0 < D; k0 += 16) {
        __syncthreads();
        if (valid) {
#pragma unroll
            for (int q = 0; q < 4; q++) {
                float4 hv = *(const float4*)(h + (size_t)n * D + k0 + 4 * q);
                float4 gv = *(const float4*)(nb + (size_t)n * D + k0 + 4 * q);
                ht[t][4 * q + 0] = hv.x; ht[t][4 * q + 1] = hv.y;
                ht[t][4 * q + 2] = hv.z; ht[t][4 * q + 3] = hv.w;
                gt[t][4 * q + 0] = gv.x; gt[t][4 * q + 1] = gv.y;
                gt[t][4 * q + 2] = gv.z; gt[t][4 * q + 3] = gv.w;
            }
        }
        __syncthreads();
        for (int kk = 0; kk < 16; kk++) {
            float a1 = ht[t][kk];
            float a2 = gt[t][kk];
            const float* __restrict__ wsr = Ws + (k0 + kk) * D;
            const float* __restrict__ wnr = Wn + (k0 + kk) * D;
#pragma unroll
            for (int c = 0; c < D; c++) {
                acc[c] = fmaf(a1, wsr[c], acc[c]);
                acc[c] = fmaf(a2, wnr[c], acc[c]);
            }
        }
    }
    if (valid) {
        float* __restrict__ orow = x1 + (size_t)n * D;
#pragma unroll
        for (int c4 = 0; c4 < D; c4 += 4) {
            float4 v;
            v.x = fmaxf(acc[c4 + 0] + b[c4 + 0], 0.f);
            v.y = fmaxf(acc[c4 + 1] + b[c4 + 1], 0.f);
            v.z = fmaxf(acc[c4 + 2] + b[c4 + 2], 0.f);
            v.w = fmaxf(acc[c4 + 3] + b[c4 + 3], 0.f);
            *(float4*)(orow + c4) = v;
        }
    }
}

// ---------------- layer-2 fold: per-graph sums ----------------
// S1[g] = sum_{n in g} x1[n];  S2[g] = sum_{n in g} (sum_{e->n} x1[src_e]) * invdeg[n]
// graph_ids sorted -> register-accumulate, flush on graph change.

__global__ void k_reduce(const float* __restrict__ x1, const int* __restrict__ rowptr,
                         const int* __restrict__ csr, const float* __restrict__ invdeg,
                         const int* __restrict__ gid, float* __restrict__ S1,
                         float* __restrict__ S2, int N) {
    int c = threadIdx.x;  // 128
    int base = blockIdx.x * RED_NB;
    float a1 = 0.f, a2 = 0.f;
    int cur = -1;
    for (int i = 0; i < RED_NB; i++) {
        int n = base + i;
        if (n >= N) break;
        int g = gid[n];
        if (g != cur) {
            if (cur >= 0) {
                atomicAdd(&S1[cur * D + c], a1);
                atomicAdd(&S2[cur * D + c], a2);
            }
            a1 = 0.f; a2 = 0.f; cur = g;
        }
        a1 += x1[(size_t)n * D + c];
        int r0 = rowptr[n], r1 = rowptr[n + 1];
        float tt = 0.f;
        for (int e = r0; e < r1; e++) tt += x1[(size_t)csr[e] * D + c];
        a2 += tt * invdeg[n];
    }
    if (cur >= 0) {
        atomicAdd(&S1[cur * D + c], a1);
        atomicAdd(&S2[cur * D + c], a2);
    }
}

// ---------------- final: hg = (S1@W2s + S2@W2n)/cnt + b2 ; out = hg@Wc + bc ----

__global__ void k_final(const float* __restrict__ S1, const float* __restrict__ S2,
                        const int* __restrict__ gcnt, const float* __restrict__ W2s,
                        const float* __restrict__ W2n, const float* __restrict__ b2,
                        const float* __restrict__ Wc, const float* __restrict__ bc,
                        float* __restrict__ out) {
    __shared__ float s1[D], s2[D], hg[D];
    int g = blockIdx.x, c = threadIdx.x;
    s1[c] = S1[g * D + c];
    s2[c] = S2[g * D + c];
    __syncthreads();
    float acc = 0.f;
#pragma unroll 8
    for (int k = 0; k < D; k++) {
        acc = fmaf(s1[k], W2s[k * D + c], acc);
        acc = fmaf(s2[k], W2n[k * D + c], acc);
    }
    int cnt = gcnt[g];
    hg[c] = (cnt > 0) ? (acc / (float)cnt + b2[c]) : 0.f;
    __syncthreads();
    if (c < N_CLS) {
        float o = bc[c];
        for (int k = 0; k < D; k++) o = fmaf(hg[k], Wc[k * N_CLS + c], o);
        out[g * N_CLS + c] = o;
    }
}

// ---------------- launch ----------------

extern "C" void kernel_launch(void* const* d_in, const int* in_sizes, int n_in,
                              void* d_out, int out_size, void* d_ws, size_t ws_size,
                              hipStream_t stream) {
    const float* h   = (const float*)d_in[0];
    const int*   src = (const int*)d_in[1];
    const int*   dst = (const int*)d_in[2];
    const int*   gid = (const int*)d_in[3];
    // d_in[4] = num_graphs scalar on device; problem-fixed = 64
    const float* W1s = (const float*)d_in[5];
    const float* W1n = (const float*)d_in[6];
    const float* b1  = (const float*)d_in[7];
    const float* W2s = (const float*)d_in[8];
    const float* W2n = (const float*)d_in[9];
    const float* b2  = (const float*)d_in[10];
    const float* Wc  = (const float*)d_in[11];
    const float* bc  = (const float*)d_in[12];
    float* out = (float*)d_out;

    const int N = in_sizes[0] / D;  // 100000
    const int E = in_sizes[1];      // 1600000

    char* w = (char*)d_ws;
    size_t off = 0;
    auto alloc = [&](size_t elems) -> void* {
        void* p = w + off;
        off += elems * 4;
        return p;
    };
    // zero-initialized region first (one memset)
    float* S1     = (float*)alloc((size_t)N_GRAPHS * D);
    float* S2     = (float*)alloc((size_t)N_GRAPHS * D);
    int*   deg    = (int*)alloc(N);
    int*   cursor = (int*)alloc(N);
    int*   gcnt   = (int*)alloc(64);
    size_t zero_bytes = off;
    int*   rowptr = (int*)alloc(N + 4);     // keep 16B alignment for later buffers
    float* invdeg = (float*)alloc(N);
    int*   bsum   = (int*)alloc(128);
    int*   boff   = (int*)alloc(128);
    int*   csr    = (int*)alloc(E);
    float* neigh  = (float*)alloc((size_t)N * D);
    float* x1     = (float*)alloc((size_t)N * D);
    (void)ws_size;

    hipMemsetAsync(d_ws, 0, zero_bytes, stream);

    int eb  = (E + 255) / 256;
    int nbk = (N + 255) / 256;
    int nch = (N + 1023) / 1024;

    k_deg<<<eb, 256, 0, stream>>>(dst, deg, E);
    k_scan1<<<nch, 1024, 0, stream>>>(deg, rowptr, bsum, N);
    k_scan2<<<1, 64, 0, stream>>>(bsum, boff, nch);
    k_scan3<<<nbk, 256, 0, stream>>>(deg, rowptr, boff, invdeg, N);
    k_scatter<<<eb, 256, 0, stream>>>(src, dst, rowptr, cursor, csr, E);
    k_hist<<<nbk, 256, 0, stream>>>(gid, gcnt, N);
    k_agg<<<N, 128, 0, stream>>>(h, rowptr, csr, invdeg, neigh);
    k_mm1<<<(N + 255) / 256, 256, 0, stream>>>(h, neigh, W1s, W1n, b1, x1, N);
    k_reduce<<<(N + RED_NB - 1) / RED_NB, 128, 0, stream>>>(x1, rowptr, csr, invdeg, gid, S1, S2, N);
    k_final<<<N_GRAPHS, 128, 0, stream>>>(S1, S2, gcnt, W2s, W2n, b2, Wc, bc, out);
}